// Round 3
// baseline (837.919 us; speedup 1.0000x reference)
//
#include <hip/hip_runtime.h>

typedef short bf16x8 __attribute__((ext_vector_type(8)));
typedef float f32x4 __attribute__((ext_vector_type(4)));
typedef unsigned short us4 __attribute__((ext_vector_type(4)));

#define B_ 16
#define S_ 2048
#define F_ 512
#define U_ 512
#define NROWS (B_ * S_)          // 32768

#define MFMA(a, b, c) __builtin_amdgcn_mfma_f32_16x16x32_bf16((a), (b), (c), 0, 0, 0)

__device__ __forceinline__ unsigned short f2b(float f) {
    unsigned u = __builtin_bit_cast(unsigned, f);
    return (unsigned short)((u + 0x7FFFu + ((u >> 16) & 1u)) >> 16);
}

// ---------------------------------------------------------------------------
// x fp32 -> bf16 row-major [32768][512]
// ---------------------------------------------------------------------------
__global__ __launch_bounds__(256) void conv_x(const float* __restrict__ x,
                                              unsigned short* __restrict__ xb)
{
    const size_t n8 = (size_t)NROWS * F_ / 8;
    const size_t stride = (size_t)gridDim.x * 256;
    for (size_t i = (size_t)blockIdx.x * 256 + threadIdx.x; i < n8; i += stride) {
        const float4 a = ((const float4*)x)[i * 2];
        const float4 b = ((const float4*)x)[i * 2 + 1];
        us4 lo, hi;
        lo.x = f2b(a.x); lo.y = f2b(a.y); lo.z = f2b(a.z); lo.w = f2b(a.w);
        hi.x = f2b(b.x); hi.y = f2b(b.y); hi.z = f2b(b.z); hi.w = f2b(b.w);
        ((us4*)xb)[i * 2]     = lo;
        ((us4*)xb)[i * 2 + 1] = hi;
    }
}

// ---------------------------------------------------------------------------
// W [k][n] fp32 -> Wt [z][n][k] bf16 (transposed)
// ---------------------------------------------------------------------------
__global__ __launch_bounds__(256) void conv_w(const float* __restrict__ Wq,
                                              const float* __restrict__ Wk,
                                              const float* __restrict__ Wv,
                                              unsigned short* __restrict__ Wt)
{
    const float* W = (blockIdx.z == 0) ? Wq : (blockIdx.z == 1) ? Wk : Wv;
    unsigned short* out = Wt + (size_t)blockIdx.z * F_ * U_;
    __shared__ float tile[32][33];
    const int k0 = blockIdx.x * 32, n0 = blockIdx.y * 32;
    const int r = threadIdx.x >> 5, c = threadIdx.x & 31;
    #pragma unroll
    for (int p = 0; p < 4; ++p)
        tile[p * 8 + r][c] = W[(size_t)(k0 + p * 8 + r) * U_ + n0 + c];
    __syncthreads();
    #pragma unroll
    for (int p = 0; p < 4; ++p)
        out[(size_t)(n0 + p * 8 + r) * F_ + k0 + c] = f2b(tile[c][p * 8 + r]);
}

// ---------------------------------------------------------------------------
// QKV GEMM, bf16 MFMA 16x16x32.  Tile 128x64, 4 waves, BK=32.
// LDS tiles XOR-swizzled at 16B granularity to kill 8-way read conflicts.
// z=0 -> Qb (pre-scaled by 1/sqrt(512)), z=1 -> Kb, z=2 -> Vt [b][u][s].
// ---------------------------------------------------------------------------
__global__ __launch_bounds__(256) void qkv_gemm(
    const unsigned short* __restrict__ xb,
    const unsigned short* __restrict__ Wt,
    unsigned short* __restrict__ Qb,
    unsigned short* __restrict__ Kb,
    unsigned short* __restrict__ Vt)
{
    __shared__ char smem[128 * 65 * 4];                 // 33280 B
    unsigned short* Xs = (unsigned short*)smem;         // [128][32] swizzled
    unsigned short* Ws = Xs + 128 * 32;                 // [64][32]  swizzled
    float* Cs = (float*)smem;                           // [128][65]

    const int z = blockIdx.z;
    const unsigned short* Wz = Wt + (size_t)z * F_ * U_;
    const int bm = blockIdx.x * 128;
    const int bn = blockIdx.y * 64;
    const int t = threadIdx.x;
    const int w = t >> 6, l = t & 63, lr = l & 15, lg = l >> 4;
    const int vxA = (lr >> 1) & 3;       // read-side slot XOR

    f32x4 acc[2][4];
    #pragma unroll
    for (int mt = 0; mt < 2; ++mt)
        #pragma unroll
        for (int nt = 0; nt < 4; ++nt)
            acc[mt][nt] = (f32x4){0.f, 0.f, 0.f, 0.f};

    for (int kc = 0; kc < 16; ++kc) {
        const int k0 = kc * 32;
        __syncthreads();
        #pragma unroll
        for (int p = 0; p < 2; ++p) {
            const int idx = p * 256 + t;
            const int row = idx >> 2, slot = idx & 3;
            const bf16x8 v =
                *(const bf16x8*)&xb[(size_t)(bm + row) * F_ + k0 + slot * 8];
            *(bf16x8*)&Xs[row * 32 + ((slot ^ ((row >> 1) & 3)) * 8)] = v;
        }
        {
            const int row = t >> 2, slot = t & 3;
            const bf16x8 v =
                *(const bf16x8*)&Wz[(size_t)(bn + row) * F_ + k0 + slot * 8];
            *(bf16x8*)&Ws[row * 32 + ((slot ^ ((row >> 1) & 3)) * 8)] = v;
        }
        __syncthreads();
        const bf16x8 a0 = *(const bf16x8*)&Xs[(w * 32 + lr) * 32 + ((lg ^ vxA) * 8)];
        const bf16x8 a1 = *(const bf16x8*)&Xs[(w * 32 + 16 + lr) * 32 + ((lg ^ vxA) * 8)];
        #pragma unroll
        for (int nt = 0; nt < 4; ++nt) {
            const bf16x8 bb = *(const bf16x8*)&Ws[(nt * 16 + lr) * 32 + ((lg ^ vxA) * 8)];
            acc[0][nt] = MFMA(a0, bb, acc[0][nt]);
            acc[1][nt] = MFMA(a1, bb, acc[1][nt]);
        }
        __syncthreads();
    }
    __syncthreads();
    #pragma unroll
    for (int mt = 0; mt < 2; ++mt)
        #pragma unroll
        for (int nt = 0; nt < 4; ++nt)
            #pragma unroll
            for (int j = 0; j < 4; ++j)
                Cs[(w * 32 + mt * 16 + lg * 4 + j) * 65 + nt * 16 + lr] = acc[mt][nt][j];
    __syncthreads();

    if (z < 2) {
        unsigned short* out = (z == 0) ? Qb : Kb;
        const float qs = (z == 0) ? 0.044194173824159216f : 1.0f;  // 1/sqrt(512)
        const int row = t >> 1, half = t & 1;
        unsigned short tmp[32];
        #pragma unroll
        for (int i = 0; i < 32; ++i) tmp[i] = f2b(Cs[row * 65 + half * 32 + i] * qs);
        #pragma unroll
        for (int v = 0; v < 4; ++v)
            *(bf16x8*)&out[(size_t)(bm + row) * U_ + bn + half * 32 + v * 8] =
                *(bf16x8*)&tmp[v * 8];
    } else {
        const int c = t >> 2, s0 = (t & 3) * 32;
        const int b = bm >> 11, sbase = (bm & 2047) + s0;
        unsigned short tmp[32];
        #pragma unroll
        for (int i = 0; i < 32; ++i) tmp[i] = f2b(Cs[(s0 + i) * 65 + c]);
        #pragma unroll
        for (int v = 0; v < 4; ++v)
            *(bf16x8*)&Vt[((size_t)(b * U_ + bn + c)) * S_ + sbase + v * 8] =
                *(bf16x8*)&tmp[v * 8];
    }
}

// ---------------------------------------------------------------------------
// Flash attention with MFMA + swizzled LDS + deferred-max softmax.
// Block = (qblk, b), 256 threads = 4 waves; wave owns 16 queries; 32 keys/iter.
// ---------------------------------------------------------------------------
__global__ __launch_bounds__(256, 2) void attn_mfma(
    const unsigned short* __restrict__ Qb,
    const unsigned short* __restrict__ Kb,
    const unsigned short* __restrict__ Vt,
    float* __restrict__ partial)
{
    __shared__ unsigned short Ks[32 * 512];      // [32 k][512 f], slot^=(row&7)
    __shared__ unsigned short Vs[512 * 32];      // [512 u][32 k], slot^=((row>>1)&3)
    __shared__ unsigned short Ps[64 * 56];       // [64 q][48 keys], padded rows

    const int qblk = blockIdx.x;        // 0..31
    const int b    = blockIdx.y;        // 0..15
    const int t = threadIdx.x;
    const int w = t >> 6, l = t & 63, lr = l & 15, lg = l >> 4;
    const int kx = lr & 7;              // Ks read-side XOR
    const int vx = (lr >> 1) & 3;       // Vs read-side XOR

    // hoist Q fragments (Q is pre-scaled by 1/sqrt(512))
    bf16x8 q[16];
    {
        const unsigned short* qg =
            Qb + (size_t)(b * S_ + qblk * 64 + w * 16 + lr) * U_ + lg * 8;
        #pragma unroll
        for (int kc = 0; kc < 16; ++kc)
            q[kc] = *(const bf16x8*)(qg + kc * 32);
    }

    f32x4 ctx[32];
    #pragma unroll
    for (int nt = 0; nt < 32; ++nt) ctx[nt] = (f32x4){0.f, 0.f, 0.f, 0.f};
    float m_i = -1e30f, l_i = 0.f;

    for (int kb = 0; kb < S_ / 32; ++kb) {
        __syncthreads();
        // ---- stage K [32][512] (global linear read, swizzled LDS write) ----
        {
            const unsigned short* kg = Kb + (size_t)(b * S_ + kb * 32) * U_;
            #pragma unroll
            for (int p = 0; p < 8; ++p) {
                const int idx = p * 256 + t;
                const int row = idx >> 6, slot = idx & 63;
                const bf16x8 v = *(const bf16x8*)&kg[row * 512 + slot * 8];
                *(bf16x8*)&Ks[row * 512 + ((slot ^ (row & 7)) * 8)] = v;
            }
            // ---- stage Vt chunk [512][32] ----
            const unsigned short* vg = Vt + (size_t)b * U_ * S_ + kb * 32;
            #pragma unroll
            for (int p = 0; p < 8; ++p) {
                const int idx = p * 256 + t;
                const int row = idx >> 2, slot = idx & 3;
                const bf16x8 v = *(const bf16x8*)&vg[(size_t)row * S_ + slot * 8];
                *(bf16x8*)&Vs[row * 32 + ((slot ^ ((row >> 1) & 3)) * 8)] = v;
            }
        }
        __syncthreads();

        // ---- QK^T (swapped): S^T[key][q] ----
        f32x4 s0 = (f32x4){0.f, 0.f, 0.f, 0.f};
        f32x4 s1 = (f32x4){0.f, 0.f, 0.f, 0.f};
        #pragma unroll
        for (int kc = 0; kc < 16; ++kc) {
            const int sl = ((kc * 4 + lg) ^ kx) * 8;
            const bf16x8 k0 = *(const bf16x8*)&Ks[lr * 512 + sl];
            const bf16x8 k1 = *(const bf16x8*)&Ks[(16 + lr) * 512 + sl];
            s0 = MFMA(k0, q[kc], s0);
            s1 = MFMA(k1, q[kc], s1);
        }

        // ---- online softmax with deferred rescale (THR=8) ----
        float mb = s0[0];
        #pragma unroll
        for (int j = 1; j < 4; ++j) mb = fmaxf(mb, s0[j]);
        #pragma unroll
        for (int j = 0; j < 4; ++j) mb = fmaxf(mb, s1[j]);
        mb = fmaxf(mb, __shfl_xor(mb, 16));
        mb = fmaxf(mb, __shfl_xor(mb, 32));

        if (!__all(mb <= m_i + 8.f)) {
            const float m_new = fmaxf(m_i, mb);
            const float alpha = __expf(m_i - m_new);
            float arow[4];
            #pragma unroll
            for (int j = 0; j < 4; ++j)
                arow[j] = __shfl(alpha, (l & 48) | (lg * 4 + j));
            #pragma unroll
            for (int nt = 0; nt < 32; ++nt)
                #pragma unroll
                for (int j = 0; j < 4; ++j) ctx[nt][j] *= arow[j];
            l_i *= alpha;
            m_i = m_new;
        }

        float p0[4], p1[4];
        float ladd = 0.f;
        #pragma unroll
        for (int j = 0; j < 4; ++j) {
            p0[j] = __expf(s0[j] - m_i);
            p1[j] = __expf(s1[j] - m_i);
            ladd += p0[j] + p1[j];
        }
        ladd += __shfl_xor(ladd, 16);
        ladd += __shfl_xor(ladd, 32);
        l_i += ladd;

        // ---- P -> A-fragment layout via per-wave-private LDS rows ----
        us4 w0, w1;
        w0.x = f2b(p0[0]); w0.y = f2b(p0[1]); w0.z = f2b(p0[2]); w0.w = f2b(p0[3]);
        w1.x = f2b(p1[0]); w1.y = f2b(p1[1]); w1.z = f2b(p1[2]); w1.w = f2b(p1[3]);
        *(us4*)&Ps[(w * 16 + lr) * 56 + lg * 4]      = w0;
        *(us4*)&Ps[(w * 16 + lr) * 56 + 16 + lg * 4] = w1;
        const bf16x8 pf = *(const bf16x8*)&Ps[(w * 16 + lr) * 56 + lg * 8];

        // ---- PV ----
        #pragma unroll
        for (int nt = 0; nt < 32; ++nt) {
            const bf16x8 vf =
                *(const bf16x8*)&Vs[(nt * 16 + lr) * 32 + ((lg ^ vx) * 8)];
            ctx[nt] = MFMA(pf, vf, ctx[nt]);
        }
    }

    // ---- epilogue: normalize, reduce the wave's 16 queries, combine waves ----
    const float inv = 1.f / l_i;
    float invr[4];
    #pragma unroll
    for (int j = 0; j < 4; ++j)
        invr[j] = __shfl(inv, (l & 48) | (lg * 4 + j));

    __syncthreads();
    float* SumBuf = (float*)Ks;            // [4][512] fp32
    #pragma unroll
    for (int nt = 0; nt < 32; ++nt) {
        float s = ctx[nt][0] * invr[0] + ctx[nt][1] * invr[1]
                + ctx[nt][2] * invr[2] + ctx[nt][3] * invr[3];
        s += __shfl_xor(s, 16);
        s += __shfl_xor(s, 32);
        if (lg == 0) SumBuf[w * 512 + nt * 16 + lr] = s;
    }
    __syncthreads();
    for (int u = t; u < 512; u += 256) {
        const float s = SumBuf[u] + SumBuf[512 + u] + SumBuf[1024 + u] + SumBuf[1536 + u];
        partial[(size_t)(b * 32 + qblk) * U_ + u] = s;
    }
}

// ---------------------------------------------------------------------------
// partial [16][32][512] -> out [16][512], mean over S
// ---------------------------------------------------------------------------
__global__ __launch_bounds__(256) void reduce_mean(
    const float* __restrict__ partial, float* __restrict__ out)
{
    const int b = blockIdx.x;
    for (int u = threadIdx.x; u < U_; u += 256) {
        float s = 0.f;
        #pragma unroll 8
        for (int p = 0; p < 32; ++p)
            s += partial[(size_t)(b * 32 + p) * U_ + u];
        out[b * U_ + u] = s * (1.0f / (float)S_);
    }
}

extern "C" void kernel_launch(void* const* d_in, const int* in_sizes, int n_in,
                              void* d_out, int out_size, void* d_ws, size_t ws_size,
                              hipStream_t stream)
{
    const float* x  = (const float*)d_in[0];
    const float* Wq = (const float*)d_in[1];
    const float* Wk = (const float*)d_in[2];
    const float* Wv = (const float*)d_in[3];
    float* out = (float*)d_out;

    unsigned short* ws = (unsigned short*)d_ws;
    const size_t XB_OFF = 0;                               // [32768][512] bf16
    const size_t WT_OFF = XB_OFF + (size_t)NROWS * F_;     // 3x[512][512] bf16
    const size_t QB_OFF = WT_OFF + 3ull * F_ * U_;
    const size_t KB_OFF = QB_OFF + (size_t)NROWS * U_;
    const size_t VT_OFF = KB_OFF + (size_t)NROWS * U_;
    const size_t END_USH = VT_OFF + (size_t)NROWS * U_;
    float* partial = (float*)(ws + END_USH);               // [16][32][512] fp32
    const size_t need = END_USH * 2 + (size_t)B_ * 32 * U_ * 4;
    if (ws_size < need) return;

    unsigned short* xb = ws + XB_OFF;
    unsigned short* Wt = ws + WT_OFF;
    unsigned short* Qb = ws + QB_OFF;
    unsigned short* Kb = ws + KB_OFF;
    unsigned short* Vt = ws + VT_OFF;

    conv_x<<<2048, 256, 0, stream>>>(x, xb);
    conv_w<<<dim3(16, 16, 3), 256, 0, stream>>>(Wq, Wk, Wv, Wt);
    qkv_gemm<<<dim3(NROWS / 128, U_ / 64, 3), 256, 0, stream>>>(xb, Wt, Qb, Kb, Vt);
    attn_mfma<<<dim3(32, 16), 256, 0, stream>>>(Qb, Kb, Vt, partial);
    reduce_mean<<<B_, 256, 0, stream>>>(partial, out);
}

// Round 4
// 448.274 us; speedup vs baseline: 1.8692x; 1.8692x over previous
//
#include <hip/hip_runtime.h>

typedef short bf16x8 __attribute__((ext_vector_type(8)));
typedef float f32x4 __attribute__((ext_vector_type(4)));
typedef unsigned short us4 __attribute__((ext_vector_type(4)));

#define B_ 16
#define S_ 2048
#define F_ 512
#define U_ 512
#define NROWS (B_ * S_)          // 32768

#define MFMA(a, b, c) __builtin_amdgcn_mfma_f32_16x16x32_bf16((a), (b), (c), 0, 0, 0)

__device__ __forceinline__ unsigned short f2b(float f) {
    unsigned u = __builtin_bit_cast(unsigned, f);
    return (unsigned short)((u + 0x7FFFu + ((u >> 16) & 1u)) >> 16);
}

// ---------------------------------------------------------------------------
// x fp32 -> bf16 row-major [32768][512]
// ---------------------------------------------------------------------------
__global__ __launch_bounds__(256) void conv_x(const float* __restrict__ x,
                                              unsigned short* __restrict__ xb)
{
    const size_t n8 = (size_t)NROWS * F_ / 8;
    const size_t stride = (size_t)gridDim.x * 256;
    for (size_t i = (size_t)blockIdx.x * 256 + threadIdx.x; i < n8; i += stride) {
        const float4 a = ((const float4*)x)[i * 2];
        const float4 b = ((const float4*)x)[i * 2 + 1];
        us4 lo, hi;
        lo.x = f2b(a.x); lo.y = f2b(a.y); lo.z = f2b(a.z); lo.w = f2b(a.w);
        hi.x = f2b(b.x); hi.y = f2b(b.y); hi.z = f2b(b.z); hi.w = f2b(b.w);
        ((us4*)xb)[i * 2]     = lo;
        ((us4*)xb)[i * 2 + 1] = hi;
    }
}

// ---------------------------------------------------------------------------
// W [k][n] fp32 -> Wt [z][n][k] bf16 (transposed)
// ---------------------------------------------------------------------------
__global__ __launch_bounds__(256) void conv_w(const float* __restrict__ Wq,
                                              const float* __restrict__ Wk,
                                              const float* __restrict__ Wv,
                                              unsigned short* __restrict__ Wt)
{
    const float* W = (blockIdx.z == 0) ? Wq : (blockIdx.z == 1) ? Wk : Wv;
    unsigned short* out = Wt + (size_t)blockIdx.z * F_ * U_;
    __shared__ float tile[32][33];
    const int k0 = blockIdx.x * 32, n0 = blockIdx.y * 32;
    const int r = threadIdx.x >> 5, c = threadIdx.x & 31;
    #pragma unroll
    for (int p = 0; p < 4; ++p)
        tile[p * 8 + r][c] = W[(size_t)(k0 + p * 8 + r) * U_ + n0 + c];
    __syncthreads();
    #pragma unroll
    for (int p = 0; p < 4; ++p)
        out[(size_t)(n0 + p * 8 + r) * F_ + k0 + c] = f2b(tile[c][p * 8 + r]);
}

// ---------------------------------------------------------------------------
// QKV GEMM, bf16 MFMA 16x16x32.  Tile 128x64, 4 waves, BK=32.
// z=0 -> Qb (pre-scaled by 1/sqrt(512)), z=1 -> Kb, z=2 -> Vt [b][u][s].
// ---------------------------------------------------------------------------
__global__ __launch_bounds__(256) void qkv_gemm(
    const unsigned short* __restrict__ xb,
    const unsigned short* __restrict__ Wt,
    unsigned short* __restrict__ Qb,
    unsigned short* __restrict__ Kb,
    unsigned short* __restrict__ Vt)
{
    __shared__ char smem[128 * 65 * 4];                 // 33280 B
    unsigned short* Xs = (unsigned short*)smem;         // [128][32] swizzled
    unsigned short* Ws = Xs + 128 * 32;                 // [64][32]  swizzled
    float* Cs = (float*)smem;                           // [128][65]

    const int z = blockIdx.z;
    const unsigned short* Wz = Wt + (size_t)z * F_ * U_;
    const int bm = blockIdx.x * 128;
    const int bn = blockIdx.y * 64;
    const int t = threadIdx.x;
    const int w = t >> 6, l = t & 63, lr = l & 15, lg = l >> 4;
    const int vxA = (lr >> 1) & 3;       // read-side slot XOR

    f32x4 acc[2][4];
    #pragma unroll
    for (int mt = 0; mt < 2; ++mt)
        #pragma unroll
        for (int nt = 0; nt < 4; ++nt)
            acc[mt][nt] = (f32x4){0.f, 0.f, 0.f, 0.f};

    for (int kc = 0; kc < 16; ++kc) {
        const int k0 = kc * 32;
        __syncthreads();
        #pragma unroll
        for (int p = 0; p < 2; ++p) {
            const int idx = p * 256 + t;
            const int row = idx >> 2, slot = idx & 3;
            const bf16x8 v =
                *(const bf16x8*)&xb[(size_t)(bm + row) * F_ + k0 + slot * 8];
            *(bf16x8*)&Xs[row * 32 + ((slot ^ ((row >> 1) & 3)) * 8)] = v;
        }
        {
            const int row = t >> 2, slot = t & 3;
            const bf16x8 v =
                *(const bf16x8*)&Wz[(size_t)(bn + row) * F_ + k0 + slot * 8];
            *(bf16x8*)&Ws[row * 32 + ((slot ^ ((row >> 1) & 3)) * 8)] = v;
        }
        __syncthreads();
        const bf16x8 a0 = *(const bf16x8*)&Xs[(w * 32 + lr) * 32 + ((lg ^ vxA) * 8)];
        const bf16x8 a1 = *(const bf16x8*)&Xs[(w * 32 + 16 + lr) * 32 + ((lg ^ vxA) * 8)];
        #pragma unroll
        for (int nt = 0; nt < 4; ++nt) {
            const bf16x8 bb = *(const bf16x8*)&Ws[(nt * 16 + lr) * 32 + ((lg ^ vxA) * 8)];
            acc[0][nt] = MFMA(a0, bb, acc[0][nt]);
            acc[1][nt] = MFMA(a1, bb, acc[1][nt]);
        }
    }
    __syncthreads();
    #pragma unroll
    for (int mt = 0; mt < 2; ++mt)
        #pragma unroll
        for (int nt = 0; nt < 4; ++nt)
            #pragma unroll
            for (int j = 0; j < 4; ++j)
                Cs[(w * 32 + mt * 16 + lg * 4 + j) * 65 + nt * 16 + lr] = acc[mt][nt][j];
    __syncthreads();

    if (z < 2) {
        unsigned short* out = (z == 0) ? Qb : Kb;
        const float qs = (z == 0) ? 0.044194173824159216f : 1.0f;  // 1/sqrt(512)
        const int row = t >> 1, half = t & 1;
        unsigned short tmp[32];
        #pragma unroll
        for (int i = 0; i < 32; ++i) tmp[i] = f2b(Cs[row * 65 + half * 32 + i] * qs);
        #pragma unroll
        for (int v = 0; v < 4; ++v)
            *(bf16x8*)&out[(size_t)(bm + row) * U_ + bn + half * 32 + v * 8] =
                *(bf16x8*)&tmp[v * 8];
    } else {
        const int c = t >> 2, s0 = (t & 3) * 32;
        const int b = bm >> 11, sbase = (bm & 2047) + s0;
        unsigned short tmp[32];
        #pragma unroll
        for (int i = 0; i < 32; ++i) tmp[i] = f2b(Cs[(s0 + i) * 65 + c]);
        #pragma unroll
        for (int v = 0; v < 4; ++v)
            *(bf16x8*)&Vt[((size_t)(b * U_ + bn + c)) * S_ + sbase + v * 8] =
                *(bf16x8*)&tmp[v * 8];
    }
}

// ---------------------------------------------------------------------------
// Flash attention v4: 512 threads = 8 waves (4 qw x 2 uw); 64 q/block;
// wave = 16 q x 256 u (ctx 64 VGPR).  XCD-phased batch mapping: all blocks
// resident on one XCD work the same b -> K/V (4 MB) L2-resident.
// Reg-prefetch staging double-buffers global->LDS across the compute phase.
// Padded LDS rows (516 / 36 shorts) give <=2-way conflicts without XOR.
// ---------------------------------------------------------------------------
__global__ __launch_bounds__(512, 2) void attn_mfma(
    const unsigned short* __restrict__ Qb,
    const unsigned short* __restrict__ Kb,
    const unsigned short* __restrict__ Vt,
    float* __restrict__ partial)
{
    __shared__ unsigned short Ks[32 * 516];        // 33.0 KB
    __shared__ unsigned short Vs[512 * 36];        // 36.9 KB
    __shared__ unsigned short Ps[128 * 36];        //  9.2 KB (8 waves x 16 rows)
    __shared__ float SumBuf[8][256];               //  8.0 KB   -> 87 KB total

    const int d = blockIdx.x;
    const int b    = (d & 7) + ((d >> 8) << 3);    // XCD-phase mapping
    const int qblk = (d >> 3) & 31;                // 0..31
    const int t = threadIdx.x;
    const int w = t >> 6;                          // 0..7
    const int qw = w >> 1, uw = w & 1;
    const int l = t & 63, lr = l & 15, lg = l >> 4;

    // ---- hoist Q fragments (pre-scaled by 1/sqrt(512)) ----
    bf16x8 q[16];
    {
        const unsigned short* qg =
            Qb + (size_t)(b * S_ + qblk * 64 + qw * 16 + lr) * U_ + lg * 8;
        #pragma unroll
        for (int kc = 0; kc < 16; ++kc)
            q[kc] = *(const bf16x8*)(qg + kc * 32);
    }

    const unsigned short* kgb = Kb + (size_t)b * S_ * U_;
    const unsigned short* vgb = Vt + (size_t)b * U_ * S_;

    bf16x8 kreg[4], vreg[4];
    // prologue: load tile kb=0 into regs
    #pragma unroll
    for (int p = 0; p < 4; ++p) {
        const int id = p * 512 + t;
        kreg[p] = *(const bf16x8*)&kgb[(size_t)(id >> 6) * U_ + (id & 63) * 8];
        vreg[p] = *(const bf16x8*)&vgb[(size_t)(id >> 2) * S_ + (id & 3) * 8];
    }

    f32x4 ctx[16];
    #pragma unroll
    for (int nt = 0; nt < 16; ++nt) ctx[nt] = (f32x4){0.f, 0.f, 0.f, 0.f};
    float m_i = -1e30f, l_i = 0.f;

    for (int kb = 0; kb < S_ / 32; ++kb) {
        __syncthreads();                 // previous iteration done reading LDS
        // publish prefetched tile (compiler inserts vmcnt wait)
        #pragma unroll
        for (int p = 0; p < 4; ++p) {
            const int id = p * 512 + t;
            *(bf16x8*)&Ks[(id >> 6) * 516 + (id & 63) * 8] = kreg[p];
            *(bf16x8*)&Vs[(id >> 2) * 36 + (id & 3) * 8]   = vreg[p];
        }
        __syncthreads();                 // tiles visible

        // issue next tile's global loads (hidden under compute below)
        const int nkb = (kb < S_ / 32 - 1) ? kb + 1 : kb;
        #pragma unroll
        for (int p = 0; p < 4; ++p) {
            const int id = p * 512 + t;
            kreg[p] = *(const bf16x8*)&kgb[(size_t)(nkb * 32 + (id >> 6)) * U_ + (id & 63) * 8];
            vreg[p] = *(const bf16x8*)&vgb[(size_t)(id >> 2) * S_ + nkb * 32 + (id & 3) * 8];
        }

        // ---- QK^T (swapped): S^T[key][q], keys 0..15 / 16..31 ----
        f32x4 s0 = (f32x4){0.f, 0.f, 0.f, 0.f};
        f32x4 s1 = (f32x4){0.f, 0.f, 0.f, 0.f};
        #pragma unroll
        for (int kc = 0; kc < 16; ++kc) {
            const bf16x8 k0 = *(const bf16x8*)&Ks[lr * 516 + kc * 32 + lg * 8];
            const bf16x8 k1 = *(const bf16x8*)&Ks[(16 + lr) * 516 + kc * 32 + lg * 8];
            s0 = MFMA(k0, q[kc], s0);
            s1 = MFMA(k1, q[kc], s1);
        }

        // ---- online softmax with deferred rescale (THR=8) ----
        float mb = s0[0];
        #pragma unroll
        for (int j = 1; j < 4; ++j) mb = fmaxf(mb, s0[j]);
        #pragma unroll
        for (int j = 0; j < 4; ++j) mb = fmaxf(mb, s1[j]);
        mb = fmaxf(mb, __shfl_xor(mb, 16));
        mb = fmaxf(mb, __shfl_xor(mb, 32));

        if (!__all(mb <= m_i + 8.f)) {
            const float m_new = fmaxf(m_i, mb);
            const float alpha = __expf(m_i - m_new);
            float arow[4];
            #pragma unroll
            for (int j = 0; j < 4; ++j)
                arow[j] = __shfl(alpha, (l & 48) | (lg * 4 + j));
            #pragma unroll
            for (int nt = 0; nt < 16; ++nt)
                #pragma unroll
                for (int j = 0; j < 4; ++j) ctx[nt][j] *= arow[j];
            l_i *= alpha;
            m_i = m_new;
        }

        float p0[4], p1[4];
        float ladd = 0.f;
        #pragma unroll
        for (int j = 0; j < 4; ++j) {
            p0[j] = __expf(s0[j] - m_i);
            p1[j] = __expf(s1[j] - m_i);
            ladd += p0[j] + p1[j];
        }
        ladd += __shfl_xor(ladd, 16);
        ladd += __shfl_xor(ladd, 32);
        l_i += ladd;

        // ---- P -> A-fragment layout via per-wave-private LDS rows ----
        us4 w0, w1;
        w0.x = f2b(p0[0]); w0.y = f2b(p0[1]); w0.z = f2b(p0[2]); w0.w = f2b(p0[3]);
        w1.x = f2b(p1[0]); w1.y = f2b(p1[1]); w1.z = f2b(p1[2]); w1.w = f2b(p1[3]);
        *(us4*)&Ps[(w * 16 + lr) * 36 + lg * 4]      = w0;
        *(us4*)&Ps[(w * 16 + lr) * 36 + 16 + lg * 4] = w1;
        const bf16x8 pf = *(const bf16x8*)&Ps[(w * 16 + lr) * 36 + lg * 8];

        // ---- PV over this wave's u-half: ctx[16q x 256u] ----
        #pragma unroll
        for (int nt = 0; nt < 16; ++nt) {
            const bf16x8 vf =
                *(const bf16x8*)&Vs[(uw * 256 + nt * 16 + lr) * 36 + lg * 8];
            ctx[nt] = MFMA(pf, vf, ctx[nt]);
        }
    }

    // ---- epilogue: normalize, sum wave's 16 queries, combine qw waves ----
    const float inv = 1.f / l_i;
    float invr[4];
    #pragma unroll
    for (int j = 0; j < 4; ++j)
        invr[j] = __shfl(inv, (l & 48) | (lg * 4 + j));

    #pragma unroll
    for (int nt = 0; nt < 16; ++nt) {
        float s = ctx[nt][0] * invr[0] + ctx[nt][1] * invr[1]
                + ctx[nt][2] * invr[2] + ctx[nt][3] * invr[3];
        s += __shfl_xor(s, 16);
        s += __shfl_xor(s, 32);
        if (lg == 0) SumBuf[w][nt * 16 + lr] = s;
    }
    __syncthreads();
    {
        const int u = t;                       // 512 threads cover 512 u
        const int uwv = u >> 8, ul = u & 255;
        const float s = SumBuf[0 * 2 + uwv][ul] + SumBuf[1 * 2 + uwv][ul]
                      + SumBuf[2 * 2 + uwv][ul] + SumBuf[3 * 2 + uwv][ul];
        partial[(size_t)(b * 32 + qblk) * U_ + u] = s;
    }
}

// ---------------------------------------------------------------------------
// partial [16][32][512] -> out [16][512], mean over S
// ---------------------------------------------------------------------------
__global__ __launch_bounds__(256) void reduce_mean(
    const float* __restrict__ partial, float* __restrict__ out)
{
    const int b = blockIdx.x;
    for (int u = threadIdx.x; u < U_; u += 256) {
        float s = 0.f;
        #pragma unroll 8
        for (int p = 0; p < 32; ++p)
            s += partial[(size_t)(b * 32 + p) * U_ + u];
        out[b * U_ + u] = s * (1.0f / (float)S_);
    }
}

extern "C" void kernel_launch(void* const* d_in, const int* in_sizes, int n_in,
                              void* d_out, int out_size, void* d_ws, size_t ws_size,
                              hipStream_t stream)
{
    const float* x  = (const float*)d_in[0];
    const float* Wq = (const float*)d_in[1];
    const float* Wk = (const float*)d_in[2];
    const float* Wv = (const float*)d_in[3];
    float* out = (float*)d_out;

    unsigned short* ws = (unsigned short*)d_ws;
    const size_t XB_OFF = 0;                               // [32768][512] bf16
    const size_t WT_OFF = XB_OFF + (size_t)NROWS * F_;     // 3x[512][512] bf16
    const size_t QB_OFF = WT_OFF + 3ull * F_ * U_;
    const size_t KB_OFF = QB_OFF + (size_t)NROWS * U_;
    const size_t VT_OFF = KB_OFF + (size_t)NROWS * U_;
    const size_t END_USH = VT_OFF + (size_t)NROWS * U_;
    float* partial = (float*)(ws + END_USH);               // [16][32][512] fp32
    const size_t need = END_USH * 2 + (size_t)B_ * 32 * U_ * 4;
    if (ws_size < need) return;

    unsigned short* xb = ws + XB_OFF;
    unsigned short* Wt = ws + WT_OFF;
    unsigned short* Qb = ws + QB_OFF;
    unsigned short* Kb = ws + KB_OFF;
    unsigned short* Vt = ws + VT_OFF;

    conv_x<<<2048, 256, 0, stream>>>(x, xb);
    conv_w<<<dim3(16, 16, 3), 256, 0, stream>>>(Wq, Wk, Wv, Wt);
    qkv_gemm<<<dim3(NROWS / 128, U_ / 64, 3), 256, 0, stream>>>(xb, Wt, Qb, Kb, Vt);
    attn_mfma<<<512, 512, 0, stream>>>(Qb, Kb, Vt, partial);
    reduce_mean<<<B_, 256, 0, stream>>>(partial, out);
}

// Round 5
// 392.708 us; speedup vs baseline: 2.1337x; 1.1415x over previous
//
#include <hip/hip_runtime.h>

typedef short bf16x8 __attribute__((ext_vector_type(8)));
typedef float f32x4 __attribute__((ext_vector_type(4)));
typedef unsigned short us4 __attribute__((ext_vector_type(4)));

#define B_ 16
#define S_ 2048
#define F_ 512
#define U_ 512
#define NROWS (B_ * S_)          // 32768

#define MFMA(a, b, c) __builtin_amdgcn_mfma_f32_16x16x32_bf16((a), (b), (c), 0, 0, 0)

__device__ __forceinline__ unsigned short f2b(float f) {
    unsigned u = __builtin_bit_cast(unsigned, f);
    return (unsigned short)((u + 0x7FFFu + ((u >> 16) & 1u)) >> 16);
}

// ---------------------------------------------------------------------------
// x fp32 -> bf16 row-major [32768][512]
// ---------------------------------------------------------------------------
__global__ __launch_bounds__(256) void conv_x(const float* __restrict__ x,
                                              unsigned short* __restrict__ xb)
{
    const size_t n8 = (size_t)NROWS * F_ / 8;
    const size_t stride = (size_t)gridDim.x * 256;
    for (size_t i = (size_t)blockIdx.x * 256 + threadIdx.x; i < n8; i += stride) {
        const float4 a = ((const float4*)x)[i * 2];
        const float4 b = ((const float4*)x)[i * 2 + 1];
        us4 lo, hi;
        lo.x = f2b(a.x); lo.y = f2b(a.y); lo.z = f2b(a.z); lo.w = f2b(a.w);
        hi.x = f2b(b.x); hi.y = f2b(b.y); hi.z = f2b(b.z); hi.w = f2b(b.w);
        ((us4*)xb)[i * 2]     = lo;
        ((us4*)xb)[i * 2 + 1] = hi;
    }
}

// ---------------------------------------------------------------------------
// W [k][n] fp32 -> Wt [z][n][k] bf16 (transposed)
// ---------------------------------------------------------------------------
__global__ __launch_bounds__(256) void conv_w(const float* __restrict__ Wq,
                                              const float* __restrict__ Wk,
                                              const float* __restrict__ Wv,
                                              unsigned short* __restrict__ Wt)
{
    const float* W = (blockIdx.z == 0) ? Wq : (blockIdx.z == 1) ? Wk : Wv;
    unsigned short* out = Wt + (size_t)blockIdx.z * F_ * U_;
    __shared__ float tile[32][33];
    const int k0 = blockIdx.x * 32, n0 = blockIdx.y * 32;
    const int r = threadIdx.x >> 5, c = threadIdx.x & 31;
    #pragma unroll
    for (int p = 0; p < 4; ++p)
        tile[p * 8 + r][c] = W[(size_t)(k0 + p * 8 + r) * U_ + n0 + c];
    __syncthreads();
    #pragma unroll
    for (int p = 0; p < 4; ++p)
        out[(size_t)(n0 + p * 8 + r) * F_ + k0 + c] = f2b(tile[c][p * 8 + r]);
}

// ---------------------------------------------------------------------------
// QKV GEMM, bf16 MFMA 16x16x32.  Tile 128x64, 4 waves, BK=32.
// z=0 -> Qb (pre-scaled by 1/sqrt(512)), z=1 -> Kb, z=2 -> Vt [b][u][s].
// ---------------------------------------------------------------------------
__global__ __launch_bounds__(256) void qkv_gemm(
    const unsigned short* __restrict__ xb,
    const unsigned short* __restrict__ Wt,
    unsigned short* __restrict__ Qb,
    unsigned short* __restrict__ Kb,
    unsigned short* __restrict__ Vt)
{
    __shared__ char smem[128 * 65 * 4];                 // 33280 B
    unsigned short* Xs = (unsigned short*)smem;         // [128][32] swizzled
    unsigned short* Ws = Xs + 128 * 32;                 // [64][32]  swizzled
    float* Cs = (float*)smem;                           // [128][65]

    const int z = blockIdx.z;
    const unsigned short* Wz = Wt + (size_t)z * F_ * U_;
    const int bm = blockIdx.x * 128;
    const int bn = blockIdx.y * 64;
    const int t = threadIdx.x;
    const int w = t >> 6, l = t & 63, lr = l & 15, lg = l >> 4;
    const int vxA = (lr >> 1) & 3;       // read-side slot XOR

    f32x4 acc[2][4];
    #pragma unroll
    for (int mt = 0; mt < 2; ++mt)
        #pragma unroll
        for (int nt = 0; nt < 4; ++nt)
            acc[mt][nt] = (f32x4){0.f, 0.f, 0.f, 0.f};

    for (int kc = 0; kc < 16; ++kc) {
        const int k0 = kc * 32;
        __syncthreads();
        #pragma unroll
        for (int p = 0; p < 2; ++p) {
            const int idx = p * 256 + t;
            const int row = idx >> 2, slot = idx & 3;
            const bf16x8 v =
                *(const bf16x8*)&xb[(size_t)(bm + row) * F_ + k0 + slot * 8];
            *(bf16x8*)&Xs[row * 32 + ((slot ^ ((row >> 1) & 3)) * 8)] = v;
        }
        {
            const int row = t >> 2, slot = t & 3;
            const bf16x8 v =
                *(const bf16x8*)&Wz[(size_t)(bn + row) * F_ + k0 + slot * 8];
            *(bf16x8*)&Ws[row * 32 + ((slot ^ ((row >> 1) & 3)) * 8)] = v;
        }
        __syncthreads();
        const bf16x8 a0 = *(const bf16x8*)&Xs[(w * 32 + lr) * 32 + ((lg ^ vxA) * 8)];
        const bf16x8 a1 = *(const bf16x8*)&Xs[(w * 32 + 16 + lr) * 32 + ((lg ^ vxA) * 8)];
        #pragma unroll
        for (int nt = 0; nt < 4; ++nt) {
            const bf16x8 bb = *(const bf16x8*)&Ws[(nt * 16 + lr) * 32 + ((lg ^ vxA) * 8)];
            acc[0][nt] = MFMA(a0, bb, acc[0][nt]);
            acc[1][nt] = MFMA(a1, bb, acc[1][nt]);
        }
    }
    __syncthreads();
    #pragma unroll
    for (int mt = 0; mt < 2; ++mt)
        #pragma unroll
        for (int nt = 0; nt < 4; ++nt)
            #pragma unroll
            for (int j = 0; j < 4; ++j)
                Cs[(w * 32 + mt * 16 + lg * 4 + j) * 65 + nt * 16 + lr] = acc[mt][nt][j];
    __syncthreads();

    if (z < 2) {
        unsigned short* out = (z == 0) ? Qb : Kb;
        const float qs = (z == 0) ? 0.044194173824159216f : 1.0f;  // 1/sqrt(512)
        const int row = t >> 1, half = t & 1;
        unsigned short tmp[32];
        #pragma unroll
        for (int i = 0; i < 32; ++i) tmp[i] = f2b(Cs[row * 65 + half * 32 + i] * qs);
        #pragma unroll
        for (int v = 0; v < 4; ++v)
            *(bf16x8*)&out[(size_t)(bm + row) * U_ + bn + half * 32 + v * 8] =
                *(bf16x8*)&tmp[v * 8];
    } else {
        const int c = t >> 2, s0 = (t & 3) * 32;
        const int b = bm >> 11, sbase = (bm & 2047) + s0;
        unsigned short tmp[32];
        #pragma unroll
        for (int i = 0; i < 32; ++i) tmp[i] = f2b(Cs[(s0 + i) * 65 + c]);
        #pragma unroll
        for (int v = 0; v < 4; ++v)
            *(bf16x8*)&Vt[((size_t)(b * U_ + bn + c)) * S_ + sbase + v * 8] =
                *(bf16x8*)&tmp[v * 8];
    }
}

// ---------------------------------------------------------------------------
// Flash attention v5: 512 threads = 8 INDEPENDENT q-waves; each wave owns
// 16 q x FULL 512 u (no uw duplication of QK^T).  Block = 128 q -> 256
// blocks, 1/CU, single pass.  XCD-phased: XCD j handles batches 2j,2j+1.
// Reg-prefetch double-stage as R4.  ctx = 32 f32x4 (AGPR-allocatable).
// ---------------------------------------------------------------------------
__global__ __launch_bounds__(512, 2) void attn_mfma(
    const unsigned short* __restrict__ Qb,
    const unsigned short* __restrict__ Kb,
    const unsigned short* __restrict__ Vt,
    float* __restrict__ partial)
{
    __shared__ unsigned short Ks[32 * 516];        // 33.0 KB
    __shared__ unsigned short Vs[512 * 36];        // 36.9 KB
    __shared__ unsigned short Ps[128 * 36];        //  9.2 KB
    __shared__ float SumBuf[8][512];               // 16.0 KB  -> 95 KB total

    const int d = blockIdx.x;                      // 0..255
    const int b    = ((d & 7) << 1) | (d >> 7);    // XCD j -> batches 2j,2j+1
    const int qblk = (d >> 3) & 15;                // 0..15 (128-q blocks)
    const int t = threadIdx.x;
    const int w = t >> 6;                          // 0..7 : q-wave id
    const int l = t & 63, lr = l & 15, lg = l >> 4;

    // ---- hoist Q fragments (pre-scaled by 1/sqrt(512)) ----
    bf16x8 q[16];
    {
        const unsigned short* qg =
            Qb + (size_t)(b * S_ + qblk * 128 + w * 16 + lr) * U_ + lg * 8;
        #pragma unroll
        for (int kc = 0; kc < 16; ++kc)
            q[kc] = *(const bf16x8*)(qg + kc * 32);
    }

    const unsigned short* kgb = Kb + (size_t)b * S_ * U_;
    const unsigned short* vgb = Vt + (size_t)b * U_ * S_;

    bf16x8 kreg[4], vreg[4];
    #pragma unroll
    for (int p = 0; p < 4; ++p) {
        const int id = p * 512 + t;
        kreg[p] = *(const bf16x8*)&kgb[(size_t)(id >> 6) * U_ + (id & 63) * 8];
        vreg[p] = *(const bf16x8*)&vgb[(size_t)(id >> 2) * S_ + (id & 3) * 8];
    }

    f32x4 ctx[32];
    #pragma unroll
    for (int nt = 0; nt < 32; ++nt) ctx[nt] = (f32x4){0.f, 0.f, 0.f, 0.f};
    float m_i = -1e30f, l_i = 0.f;

    for (int kb = 0; kb < S_ / 32; ++kb) {
        __syncthreads();                 // previous iteration done reading LDS
        // publish prefetched tile
        #pragma unroll
        for (int p = 0; p < 4; ++p) {
            const int id = p * 512 + t;
            *(bf16x8*)&Ks[(id >> 6) * 516 + (id & 63) * 8] = kreg[p];
            *(bf16x8*)&Vs[(id >> 2) * 36 + (id & 3) * 8]   = vreg[p];
        }
        __syncthreads();                 // tiles visible

        // issue next tile's global loads (hidden under compute below)
        const int nkb = (kb < S_ / 32 - 1) ? kb + 1 : kb;
        #pragma unroll
        for (int p = 0; p < 4; ++p) {
            const int id = p * 512 + t;
            kreg[p] = *(const bf16x8*)&kgb[(size_t)(nkb * 32 + (id >> 6)) * U_ + (id & 63) * 8];
            vreg[p] = *(const bf16x8*)&vgb[(size_t)(id >> 2) * S_ + nkb * 32 + (id & 3) * 8];
        }

        // ---- QK^T (swapped): S^T[key][q], keys 0..15 / 16..31 ----
        f32x4 s0 = (f32x4){0.f, 0.f, 0.f, 0.f};
        f32x4 s1 = (f32x4){0.f, 0.f, 0.f, 0.f};
        #pragma unroll
        for (int kc = 0; kc < 16; ++kc) {
            const bf16x8 k0 = *(const bf16x8*)&Ks[lr * 516 + kc * 32 + lg * 8];
            const bf16x8 k1 = *(const bf16x8*)&Ks[(16 + lr) * 516 + kc * 32 + lg * 8];
            s0 = MFMA(k0, q[kc], s0);
            s1 = MFMA(k1, q[kc], s1);
        }

        // ---- online softmax with deferred rescale (THR=8) ----
        float mb = s0[0];
        #pragma unroll
        for (int j = 1; j < 4; ++j) mb = fmaxf(mb, s0[j]);
        #pragma unroll
        for (int j = 0; j < 4; ++j) mb = fmaxf(mb, s1[j]);
        mb = fmaxf(mb, __shfl_xor(mb, 16));
        mb = fmaxf(mb, __shfl_xor(mb, 32));

        if (!__all(mb <= m_i + 8.f)) {
            const float m_new = fmaxf(m_i, mb);
            const float alpha = __expf(m_i - m_new);
            float arow[4];
            #pragma unroll
            for (int j = 0; j < 4; ++j)
                arow[j] = __shfl(alpha, (l & 48) | (lg * 4 + j));
            #pragma unroll
            for (int nt = 0; nt < 32; ++nt)
                #pragma unroll
                for (int j = 0; j < 4; ++j) ctx[nt][j] *= arow[j];
            l_i *= alpha;
            m_i = m_new;
        }

        float p0[4], p1[4];
        float ladd = 0.f;
        #pragma unroll
        for (int j = 0; j < 4; ++j) {
            p0[j] = __expf(s0[j] - m_i);
            p1[j] = __expf(s1[j] - m_i);
            ladd += p0[j] + p1[j];
        }
        ladd += __shfl_xor(ladd, 16);
        ladd += __shfl_xor(ladd, 32);
        l_i += ladd;

        // ---- P -> A-fragment layout via per-wave-private LDS rows ----
        us4 w0, w1;
        w0.x = f2b(p0[0]); w0.y = f2b(p0[1]); w0.z = f2b(p0[2]); w0.w = f2b(p0[3]);
        w1.x = f2b(p1[0]); w1.y = f2b(p1[1]); w1.z = f2b(p1[2]); w1.w = f2b(p1[3]);
        *(us4*)&Ps[(w * 16 + lr) * 36 + lg * 4]      = w0;
        *(us4*)&Ps[(w * 16 + lr) * 36 + 16 + lg * 4] = w1;
        const bf16x8 pf = *(const bf16x8*)&Ps[(w * 16 + lr) * 36 + lg * 8];

        // ---- PV over full 512 u: ctx[16q x 512u] ----
        #pragma unroll
        for (int nt = 0; nt < 32; ++nt) {
            const bf16x8 vf = *(const bf16x8*)&Vs[(nt * 16 + lr) * 36 + lg * 8];
            ctx[nt] = MFMA(pf, vf, ctx[nt]);
        }
    }

    // ---- epilogue: normalize, sum wave's 16 queries, combine 8 waves ----
    const float inv = 1.f / l_i;
    float invr[4];
    #pragma unroll
    for (int j = 0; j < 4; ++j)
        invr[j] = __shfl(inv, (l & 48) | (lg * 4 + j));

    #pragma unroll
    for (int nt = 0; nt < 32; ++nt) {
        float s = ctx[nt][0] * invr[0] + ctx[nt][1] * invr[1]
                + ctx[nt][2] * invr[2] + ctx[nt][3] * invr[3];
        s += __shfl_xor(s, 16);
        s += __shfl_xor(s, 32);
        if (lg == 0) SumBuf[w][nt * 16 + lr] = s;
    }
    __syncthreads();
    {
        const int u = t;                       // 512 threads cover 512 u
        float s = 0.f;
        #pragma unroll
        for (int ww = 0; ww < 8; ++ww) s += SumBuf[ww][u];
        partial[(size_t)(b * 16 + qblk) * U_ + u] = s;
    }
}

// ---------------------------------------------------------------------------
// partial [16][16][512] -> out [16][512], mean over S
// ---------------------------------------------------------------------------
__global__ __launch_bounds__(256) void reduce_mean(
    const float* __restrict__ partial, float* __restrict__ out)
{
    const int b = blockIdx.x;
    for (int u = threadIdx.x; u < U_; u += 256) {
        float s = 0.f;
        #pragma unroll
        for (int p = 0; p < 16; ++p)
            s += partial[(size_t)(b * 16 + p) * U_ + u];
        out[b * U_ + u] = s * (1.0f / (float)S_);
    }
}

extern "C" void kernel_launch(void* const* d_in, const int* in_sizes, int n_in,
                              void* d_out, int out_size, void* d_ws, size_t ws_size,
                              hipStream_t stream)
{
    const float* x  = (const float*)d_in[0];
    const float* Wq = (const float*)d_in[1];
    const float* Wk = (const float*)d_in[2];
    const float* Wv = (const float*)d_in[3];
    float* out = (float*)d_out;

    unsigned short* ws = (unsigned short*)d_ws;
    const size_t XB_OFF = 0;                               // [32768][512] bf16
    const size_t WT_OFF = XB_OFF + (size_t)NROWS * F_;     // 3x[512][512] bf16
    const size_t QB_OFF = WT_OFF + 3ull * F_ * U_;
    const size_t KB_OFF = QB_OFF + (size_t)NROWS * U_;
    const size_t VT_OFF = KB_OFF + (size_t)NROWS * U_;
    const size_t END_USH = VT_OFF + (size_t)NROWS * U_;
    float* partial = (float*)(ws + END_USH);               // [16][16][512] fp32
    const size_t need = END_USH * 2 + (size_t)B_ * 16 * U_ * 4;
    if (ws_size < need) return;

    unsigned short* xb = ws + XB_OFF;
    unsigned short* Wt = ws + WT_OFF;
    unsigned short* Qb = ws + QB_OFF;
    unsigned short* Kb = ws + KB_OFF;
    unsigned short* Vt = ws + VT_OFF;

    conv_x<<<2048, 256, 0, stream>>>(x, xb);
    conv_w<<<dim3(16, 16, 3), 256, 0, stream>>>(Wq, Wk, Wv, Wt);
    qkv_gemm<<<dim3(NROWS / 128, U_ / 64, 3), 256, 0, stream>>>(xb, Wt, Qb, Kb, Vt);
    attn_mfma<<<256, 512, 0, stream>>>(Qb, Kb, Vt, partial);
    reduce_mean<<<B_, 256, 0, stream>>>(partial, out);
}